// Round 1
// baseline (1029.075 us; speedup 1.0000x reference)
//
#include <hip/hip_runtime.h>
#include <hip/hip_bf16.h>
#include <stdint.h>

#define NN 8192      // nodes
#define NE 16384     // hyperedges
#define HIDW 64      // feature width
#define NNZ_CAP 655360

// ---------------- workspace layout (bytes) ----------------
#define OFF_NNZ      0u
#define OFF_ROWCNT   256u
#define OFF_COLCNT   (OFF_ROWCNT + NN*4u)          // 33024
#define OFF_ROWDEN   (OFF_COLCNT + NE*4u)          // 98560
#define OFF_COLDEN   (OFF_ROWDEN + NN*4u)          // 131328
#define OFF_ROWCUR   (OFF_COLDEN + NE*4u)          // 196864
#define OFF_COLCUR   (OFF_ROWCUR + NN*4u)          // 229632
#define MEMSET_BYTES (OFF_COLCUR + NE*4u)          // 295168 — everything above zeroed
#define OFF_ENORM    MEMSET_BYTES                  // edge_norm [NE]
#define OFF_NNORM    (OFF_ENORM + NE*4u)
#define OFF_RSCALE   (OFF_NNORM + NN*4u)
#define OFF_CSCALE   (OFF_RSCALE + NN*4u)
#define OFF_ROWPTR   (OFF_CSCALE + NE*4u)
#define OFF_COLPTR   (OFF_ROWPTR + NN*4u)
#define OFF_COO      (OFF_COLPTR + NE*4u)
#define OFF_CSRCOL   (OFF_COO + NNZ_CAP*4u)
#define OFF_CSCROW   (OFF_CSRCOL + NNZ_CAP*4u)
#define OFF_Y0       (OFF_CSCROW + NNZ_CAP*4u)
#define OFF_X1PRE    (OFF_Y0 + NN*HIDW*4u)
#define OFF_Z1       (OFF_X1PRE + NE*HIDW*4u)
// total = OFF_Z1 + NE*HIDW*4 ≈ 18.1 MB

// K1: one pass over B1. Each block owns 4 complete rows (65536 elements).
__global__ __launch_bounds__(256) void k_scan(const float* __restrict__ B1,
        uint32_t* __restrict__ nnz_counter, uint32_t* __restrict__ row_cnt,
        uint32_t* __restrict__ col_cnt, uint32_t* __restrict__ coo) {
    __shared__ uint32_t buf[2048];
    __shared__ uint32_t cnt, base_s;
    __shared__ uint32_t rowc[4];
    const int tid = threadIdx.x;
    if (tid == 0) cnt = 0;
    if (tid < 4) rowc[tid] = 0;
    __syncthreads();
    const long long blockBase = (long long)blockIdx.x * 65536;
    const int row0 = blockIdx.x * 4;
    for (int it = 0; it < 64; ++it) {
        int local = it * 1024 + tid * 4;            // 0..65535 within block tile
        float4 v = *reinterpret_cast<const float4*>(B1 + blockBase + local);
        int r  = local >> 14;                        // which of the 4 rows
        int j0 = local & 16383;
        float vs[4] = {v.x, v.y, v.z, v.w};
        #pragma unroll
        for (int q = 0; q < 4; ++q) {
            if (vs[q] != 0.0f) {
                uint32_t i = (uint32_t)(row0 + r);
                uint32_t j = (uint32_t)(j0 + q);
                uint32_t p = atomicAdd(&cnt, 1u);
                buf[p] = (i << 14) | j;
                atomicAdd(&rowc[r], 1u);
                atomicAdd(&col_cnt[j], 1u);
            }
        }
        __syncthreads();
        if (cnt >= 1024) {                           // flush (uniform decision)
            if (tid == 0) base_s = atomicAdd(nnz_counter, cnt);
            __syncthreads();
            uint32_t c = cnt, b = base_s;
            for (uint32_t k = tid; k < c; k += 256) coo[b + k] = buf[k];
            __syncthreads();
            if (tid == 0) cnt = 0;
            __syncthreads();
        }
    }
    if (tid == 0) base_s = atomicAdd(nnz_counter, cnt);
    __syncthreads();
    uint32_t c = cnt, b = base_s;
    for (uint32_t k = tid; k < c; k += 256) coo[b + k] = buf[k];
    if (tid < 4) row_cnt[row0 + tid] = rowc[tid];
}

__global__ void k_norms(const uint32_t* __restrict__ row_cnt,
                        const uint32_t* __restrict__ col_cnt,
                        float* __restrict__ node_norm, float* __restrict__ edge_norm) {
    int idx = blockIdx.x * blockDim.x + threadIdx.x;
    if (idx < NE) { float s = (float)col_cnt[idx]; edge_norm[idx] = 1.0f / (s * sqrtf(s)); }
    if (idx < NN) { float s = (float)row_cnt[idx]; node_norm[idx] = 1.0f / sqrtf(s); }
}

// exclusive prefix scan, single block of 1024 threads, n multiple of 1024
__global__ __launch_bounds__(1024) void k_prefix(const uint32_t* __restrict__ in,
                                                 uint32_t* __restrict__ out, int n) {
    __shared__ uint32_t s[1024];
    __shared__ uint32_t carry;
    int tid = threadIdx.x;
    if (tid == 0) carry = 0;
    __syncthreads();
    for (int base = 0; base < n; base += 1024) {
        uint32_t v = in[base + tid];
        s[tid] = v;
        __syncthreads();
        for (int off = 1; off < 1024; off <<= 1) {
            uint32_t t = (tid >= off) ? s[tid - off] : 0u;
            __syncthreads();
            s[tid] += t;
            __syncthreads();
        }
        out[base + tid] = carry + s[tid] - v;   // exclusive
        __syncthreads();
        if (tid == 1023) carry += s[1023];
        __syncthreads();
    }
}

__global__ void k_scatter(const uint32_t* __restrict__ nnz_counter,
        const uint32_t* __restrict__ coo,
        const uint32_t* __restrict__ row_ptr, const uint32_t* __restrict__ col_ptr,
        uint32_t* __restrict__ row_cur, uint32_t* __restrict__ col_cur,
        uint32_t* __restrict__ csr_col, uint32_t* __restrict__ csc_row,
        const float* __restrict__ edge_norm, const float* __restrict__ node_norm,
        float* __restrict__ row_den, float* __restrict__ col_den) {
    uint32_t nnz = *nnz_counter;
    uint32_t idx = blockIdx.x * blockDim.x + threadIdx.x;
    if (idx >= nnz) return;
    uint32_t pk = coo[idx];
    uint32_t i = pk >> 14, j = pk & 16383u;
    uint32_t p = row_ptr[i] + atomicAdd(&row_cur[i], 1u);
    csr_col[p] = j;
    uint32_t q = col_ptr[j] + atomicAdd(&col_cur[j], 1u);
    csc_row[q] = i;
    atomicAdd(&row_den[i], edge_norm[j]);
    atomicAdd(&col_den[j], node_norm[i]);
}

__global__ void k_scales(const float* __restrict__ row_den, const float* __restrict__ col_den,
        const float* __restrict__ node_norm, const float* __restrict__ edge_norm,
        float* __restrict__ rowscale, float* __restrict__ colscale) {
    int idx = blockIdx.x * blockDim.x + threadIdx.x;
    if (idx < NN) rowscale[idx] = node_norm[idx] / row_den[idx];
    if (idx < NE) colscale[idx] = edge_norm[idx] / col_den[idx];
}

// Y[R,64] = X[R,64] @ W[64,64]; block = 4 rows x 64 cols
__global__ __launch_bounds__(256) void k_gemm64(const float* __restrict__ X,
        const float* __restrict__ W, float* __restrict__ Y) {
    __shared__ float ws[64 * 64];
    __shared__ float xs[4][64];
    int tid = threadIdx.x;
    int c = tid & 63, rr = tid >> 6;
    for (int k = tid; k < 4096; k += 256) ws[k] = W[k];
    int row0 = blockIdx.x * 4;
    xs[rr][c] = X[(row0 + rr) * 64 + c];
    __syncthreads();
    float acc = 0.f;
    #pragma unroll
    for (int k = 0; k < 64; ++k) acc = fmaf(xs[rr][k], ws[k * 64 + c], acc);
    Y[(row0 + rr) * 64 + c] = acc;
}

// x1[j,:] = colscale[j] * sum_{i in col j} rowscale[i]*y0[i,:] + b01 ; one wave per edge
__global__ __launch_bounds__(256) void k_edge_gather(
        const uint32_t* __restrict__ col_ptr, const uint32_t* __restrict__ col_cnt,
        const uint32_t* __restrict__ csc_row, const float* __restrict__ rowscale,
        const float* __restrict__ colscale, const float* __restrict__ y0,
        const float* __restrict__ bias01, float* __restrict__ x1pre,
        float* __restrict__ out1) {
    int w = threadIdx.x >> 6, lane = threadIdx.x & 63;
    int j = blockIdx.x * 4 + w;
    uint32_t s = col_ptr[j], e = s + col_cnt[j];
    float acc = 0.f;
    for (uint32_t t = s; t < e; ++t) {
        uint32_t i = csc_row[t];
        acc = fmaf(rowscale[i], y0[i * 64 + lane], acc);
    }
    float val = colscale[j] * acc + bias01[lane];
    x1pre[j * 64 + lane] = val;
    out1[j * 64 + lane] = fmaxf(val, 0.f);
}

// out0[i,:] = relu(rowscale[i] * sum_{j in row i} colscale[j]*z1[j,:] + b10)
__global__ __launch_bounds__(256) void k_node_gather(
        const uint32_t* __restrict__ row_ptr, const uint32_t* __restrict__ row_cnt,
        const uint32_t* __restrict__ csr_col, const float* __restrict__ colscale,
        const float* __restrict__ rowscale, const float* __restrict__ z1,
        const float* __restrict__ bias10, float* __restrict__ out0) {
    int w = threadIdx.x >> 6, lane = threadIdx.x & 63;
    int i = blockIdx.x * 4 + w;
    uint32_t s = row_ptr[i], e = s + row_cnt[i];
    float acc = 0.f;
    for (uint32_t t = s; t < e; ++t) {
        uint32_t j = csr_col[t];
        acc = fmaf(colscale[j], z1[j * 64 + lane], acc);
    }
    out0[i * 64 + lane] = fmaxf(rowscale[i] * acc + bias10[lane], 0.f);
}

extern "C" void kernel_launch(void* const* d_in, const int* in_sizes, int n_in,
                              void* d_out, int out_size, void* d_ws, size_t ws_size,
                              hipStream_t stream) {
    const float* x0  = (const float*)d_in[0];
    const float* B1  = (const float*)d_in[1];
    const float* W0  = (const float*)d_in[2];
    const float* W1  = (const float*)d_in[3];
    const float* b01 = (const float*)d_in[4];
    const float* b10 = (const float*)d_in[5];
    float* out = (float*)d_out;
    char* ws = (char*)d_ws;

    uint32_t* nnz      = (uint32_t*)(ws + OFF_NNZ);
    uint32_t* row_cnt  = (uint32_t*)(ws + OFF_ROWCNT);
    uint32_t* col_cnt  = (uint32_t*)(ws + OFF_COLCNT);
    float*    row_den  = (float*)(ws + OFF_ROWDEN);
    float*    col_den  = (float*)(ws + OFF_COLDEN);
    uint32_t* row_cur  = (uint32_t*)(ws + OFF_ROWCUR);
    uint32_t* col_cur  = (uint32_t*)(ws + OFF_COLCUR);
    float*    enorm    = (float*)(ws + OFF_ENORM);
    float*    nnorm    = (float*)(ws + OFF_NNORM);
    float*    rscale   = (float*)(ws + OFF_RSCALE);
    float*    cscale   = (float*)(ws + OFF_CSCALE);
    uint32_t* row_ptr  = (uint32_t*)(ws + OFF_ROWPTR);
    uint32_t* col_ptr  = (uint32_t*)(ws + OFF_COLPTR);
    uint32_t* coo      = (uint32_t*)(ws + OFF_COO);
    uint32_t* csr_col  = (uint32_t*)(ws + OFF_CSRCOL);
    uint32_t* csc_row  = (uint32_t*)(ws + OFF_CSCROW);
    float*    y0       = (float*)(ws + OFF_Y0);
    float*    x1pre    = (float*)(ws + OFF_X1PRE);
    float*    z1       = (float*)(ws + OFF_Z1);

    hipMemsetAsync(d_ws, 0, MEMSET_BYTES, stream);

    k_scan<<<2048, 256, 0, stream>>>(B1, nnz, row_cnt, col_cnt, coo);
    k_norms<<<64, 256, 0, stream>>>(row_cnt, col_cnt, nnorm, enorm);
    k_prefix<<<1, 1024, 0, stream>>>(row_cnt, row_ptr, NN);
    k_prefix<<<1, 1024, 0, stream>>>(col_cnt, col_ptr, NE);
    k_scatter<<<NNZ_CAP / 256, 256, 0, stream>>>(nnz, coo, row_ptr, col_ptr,
            row_cur, col_cur, csr_col, csc_row, enorm, nnorm, row_den, col_den);
    k_scales<<<64, 256, 0, stream>>>(row_den, col_den, nnorm, enorm, rscale, cscale);
    k_gemm64<<<NN / 4, 256, 0, stream>>>(x0, W0, y0);
    k_edge_gather<<<NE / 4, 256, 0, stream>>>(col_ptr, col_cnt, csc_row,
            rscale, cscale, y0, b01, x1pre, out + NN * HIDW);
    k_gemm64<<<NE / 4, 256, 0, stream>>>(x1pre, W1, z1);
    k_node_gather<<<NN / 4, 256, 0, stream>>>(row_ptr, row_cnt, csr_col,
            cscale, rscale, z1, b10, out);
}

// Round 2
// 816.931 us; speedup vs baseline: 1.2597x; 1.2597x over previous
//
#include <hip/hip_runtime.h>
#include <hip/hip_bf16.h>
#include <stdint.h>

#define NN 8192      // nodes
#define NE 16384     // hyperedges
#define HIDW 64      // feature width
#define RCAP 128     // max row degree bucket (Poisson lambda~67, P(>=128) ~ 1e-13/row)
#define CCAP 96      // max col degree bucket (Poisson lambda~34, P(>=96)  ~ 1e-15/col)

// ---------------- workspace layout (bytes) ----------------
#define OFF_ROWCNT   0u
#define OFF_COLCNT   (OFF_ROWCNT + NN*4u)              // 32768
#define MEMSET_BYTES (OFF_COLCNT + NE*4u)              // 98304 — counters zeroed
#define OFF_ENORM    MEMSET_BYTES
#define OFF_NNORM    (OFF_ENORM + NE*4u)
#define OFF_RSCALE   (OFF_NNORM + NN*4u)
#define OFF_CSCALE   (OFF_RSCALE + NN*4u)
#define OFF_CSR      (OFF_CSCALE + NE*4u)              // [NN][RCAP] u32 = 4 MB
#define OFF_CSC      (OFF_CSR + NN*RCAP*4u)            // [NE][CCAP] u32 = 6 MB
#define OFF_Y0       (OFF_CSC + (size_t)NE*CCAP*4u)    // [NN][64]  f32 (pre-scaled by rscale)
#define OFF_X1PRE    (OFF_Y0 + NN*HIDW*4u)             // [NE][64]  f32
#define OFF_Z1       (OFF_X1PRE + (size_t)NE*HIDW*4u)  // [NE][64]  f32 (pre-scaled by cscale)
// total ~ 20.3 MB

// One block per row: single coalesced float4 pass over B1, building CSR + CSC
// buckets directly. Row cursor in LDS (no contention), col cursor global atomic.
__global__ __launch_bounds__(256) void k_scan(const float* __restrict__ B1,
        uint32_t* __restrict__ row_cnt, uint32_t* __restrict__ col_cnt,
        uint32_t* __restrict__ csr_col, uint32_t* __restrict__ csc_row) {
    __shared__ uint32_t rcur;
    const int tid = threadIdx.x;
    const int i = blockIdx.x;
    if (tid == 0) rcur = 0;
    __syncthreads();
    const long long base = (long long)i * NE;
    const int phase = i & 15;                   // stagger to decorrelate col atomics
    for (int it0 = 0; it0 < 16; ++it0) {
        int it = (it0 + phase) & 15;
        int local = it * 1024 + tid * 4;        // 0..16383
        float4 v = *reinterpret_cast<const float4*>(B1 + base + local);
        float vs[4] = {v.x, v.y, v.z, v.w};
        #pragma unroll
        for (int q = 0; q < 4; ++q) {
            if (vs[q] != 0.0f) {
                uint32_t j = (uint32_t)(local + q);
                uint32_t p = atomicAdd(&rcur, 1u);
                if (p < RCAP) csr_col[(uint32_t)i * RCAP + p] = j;
                uint32_t qq = atomicAdd(&col_cnt[j], 1u);
                if (qq < CCAP) csc_row[j * CCAP + qq] = (uint32_t)i;
            }
        }
    }
    __syncthreads();
    if (tid == 0) row_cnt[i] = (rcur < RCAP) ? rcur : RCAP;
}

__global__ void k_norms(const uint32_t* __restrict__ row_cnt,
                        const uint32_t* __restrict__ col_cnt,
                        float* __restrict__ node_norm, float* __restrict__ edge_norm) {
    int idx = blockIdx.x * blockDim.x + threadIdx.x;
    if (idx < NE) { float s = (float)col_cnt[idx]; edge_norm[idx] = 1.0f / (s * sqrtf(s)); }
    if (idx < NN) { float s = (float)row_cnt[idx]; node_norm[idx] = 1.0f / sqrtf(s); }
}

// One wave per row (units 0..NN-1) or col (units NN..NN+NE-1):
// rscale[i] = nnorm[i] / sum_j enorm[csr[i]], cscale[j] = enorm[j] / sum_i nnorm[csc[j]]
__global__ __launch_bounds__(256) void k_scales(
        const uint32_t* __restrict__ row_cnt, const uint32_t* __restrict__ col_cnt,
        const uint32_t* __restrict__ csr_col, const uint32_t* __restrict__ csc_row,
        const float* __restrict__ node_norm, const float* __restrict__ edge_norm,
        float* __restrict__ rowscale, float* __restrict__ colscale) {
    int w = blockIdx.x * 4 + (threadIdx.x >> 6);
    int lane = threadIdx.x & 63;
    float s = 0.f;
    if (w < NN) {
        uint32_t c = row_cnt[w];
        const uint32_t* p = csr_col + (uint32_t)w * RCAP;
        for (uint32_t t = lane; t < c; t += 64) s += edge_norm[p[t]];
        #pragma unroll
        for (int off = 32; off >= 1; off >>= 1) s += __shfl_xor(s, off);
        if (lane == 0) rowscale[w] = node_norm[w] / s;
    } else {
        int j = w - NN;
        uint32_t c = col_cnt[j]; if (c > CCAP) c = CCAP;
        const uint32_t* p = csc_row + (uint32_t)j * CCAP;
        for (uint32_t t = lane; t < c; t += 64) s += node_norm[p[t]];
        #pragma unroll
        for (int off = 32; off >= 1; off >>= 1) s += __shfl_xor(s, off);
        if (lane == 0) colscale[j] = edge_norm[j] / s;
    }
}

// Y[r,:] = scale[r] * (X[r,:] @ W);  block = 4 rows x 64 cols
__global__ __launch_bounds__(256) void k_gemm64(const float* __restrict__ X,
        const float* __restrict__ W, const float* __restrict__ scale,
        float* __restrict__ Y) {
    __shared__ float ws[64 * 64];
    __shared__ float xs[4][64];
    int tid = threadIdx.x;
    int c = tid & 63, rr = tid >> 6;
    for (int k = tid; k < 4096; k += 256) ws[k] = W[k];
    int row0 = blockIdx.x * 4;
    xs[rr][c] = X[(row0 + rr) * 64 + c];
    __syncthreads();
    float acc = 0.f;
    #pragma unroll
    for (int k = 0; k < 64; ++k) acc = fmaf(xs[rr][k], ws[k * 64 + c], acc);
    Y[(row0 + rr) * 64 + c] = scale[row0 + rr] * acc;
}

// x1[j,:] = colscale[j] * sum_{i in col j} y0s[i,:] + b01  (y0s pre-scaled by rowscale)
__global__ __launch_bounds__(256) void k_edge_gather(
        const uint32_t* __restrict__ col_cnt, const uint32_t* __restrict__ csc_row,
        const float* __restrict__ colscale, const float* __restrict__ y0s,
        const float* __restrict__ bias01, float* __restrict__ x1pre,
        float* __restrict__ out1) {
    int w = threadIdx.x >> 6, lane = threadIdx.x & 63;
    int j = blockIdx.x * 4 + w;
    uint32_t e = col_cnt[j]; if (e > CCAP) e = CCAP;
    const uint32_t* p = csc_row + (uint32_t)j * CCAP;
    float acc = 0.f;
    for (uint32_t t = 0; t < e; ++t) {
        uint32_t i = p[t];
        acc += y0s[i * 64 + lane];
    }
    float val = colscale[j] * acc + bias01[lane];
    x1pre[j * 64 + lane] = val;
    out1[j * 64 + lane] = fmaxf(val, 0.f);
}

// out0[i,:] = relu(rowscale[i] * sum_{j in row i} z1s[j,:] + b10)  (z1s pre-scaled by colscale)
__global__ __launch_bounds__(256) void k_node_gather(
        const uint32_t* __restrict__ row_cnt, const uint32_t* __restrict__ csr_col,
        const float* __restrict__ rowscale, const float* __restrict__ z1s,
        const float* __restrict__ bias10, float* __restrict__ out0) {
    int w = threadIdx.x >> 6, lane = threadIdx.x & 63;
    int i = blockIdx.x * 4 + w;
    uint32_t e = row_cnt[i];
    const uint32_t* p = csr_col + (uint32_t)i * RCAP;
    float acc = 0.f;
    for (uint32_t t = 0; t < e; ++t) {
        uint32_t j = p[t];
        acc += z1s[j * 64 + lane];
    }
    out0[i * 64 + lane] = fmaxf(rowscale[i] * acc + bias10[lane], 0.f);
}

extern "C" void kernel_launch(void* const* d_in, const int* in_sizes, int n_in,
                              void* d_out, int out_size, void* d_ws, size_t ws_size,
                              hipStream_t stream) {
    const float* x0  = (const float*)d_in[0];
    const float* B1  = (const float*)d_in[1];
    const float* W0  = (const float*)d_in[2];
    const float* W1  = (const float*)d_in[3];
    const float* b01 = (const float*)d_in[4];
    const float* b10 = (const float*)d_in[5];
    float* out = (float*)d_out;
    char* ws = (char*)d_ws;

    uint32_t* row_cnt = (uint32_t*)(ws + OFF_ROWCNT);
    uint32_t* col_cnt = (uint32_t*)(ws + OFF_COLCNT);
    float*    enorm   = (float*)(ws + OFF_ENORM);
    float*    nnorm   = (float*)(ws + OFF_NNORM);
    float*    rscale  = (float*)(ws + OFF_RSCALE);
    float*    cscale  = (float*)(ws + OFF_CSCALE);
    uint32_t* csr_col = (uint32_t*)(ws + OFF_CSR);
    uint32_t* csc_row = (uint32_t*)(ws + OFF_CSC);
    float*    y0      = (float*)(ws + OFF_Y0);
    float*    x1pre   = (float*)(ws + OFF_X1PRE);
    float*    z1      = (float*)(ws + OFF_Z1);

    hipMemsetAsync(d_ws, 0, MEMSET_BYTES, stream);

    k_scan<<<NN, 256, 0, stream>>>(B1, row_cnt, col_cnt, csr_col, csc_row);
    k_norms<<<NE / 256, 256, 0, stream>>>(row_cnt, col_cnt, nnorm, enorm);
    k_scales<<<(NN + NE) / 4, 256, 0, stream>>>(row_cnt, col_cnt, csr_col, csc_row,
            nnorm, enorm, rscale, cscale);
    k_gemm64<<<NN / 4, 256, 0, stream>>>(x0, W0, rscale, y0);
    k_edge_gather<<<NE / 4, 256, 0, stream>>>(col_cnt, csc_row, cscale, y0,
            b01, x1pre, out + NN * HIDW);
    k_gemm64<<<NE / 4, 256, 0, stream>>>(x1pre, W1, cscale, z1);
    k_node_gather<<<NN / 4, 256, 0, stream>>>(row_cnt, csr_col, rscale, z1, b10, out);
}

// Round 3
// 766.871 us; speedup vs baseline: 1.3419x; 1.0653x over previous
//
#include <hip/hip_runtime.h>
#include <hip/hip_bf16.h>
#include <stdint.h>

#define NN 8192      // nodes
#define NE 16384     // hyperedges
#define RCAP 128     // max row degree bucket (Poisson lambda~67)
#define CCAP 96      // max col degree bucket (Poisson lambda~34)

// ---------------- workspace layout (bytes) ----------------
#define OFF_COLCNT   0u
#define MEMSET_BYTES (NE*4u)                           // only col_cnt needs zeroing
#define OFF_ROWCNT   MEMSET_BYTES
#define OFF_RSCALE   (OFF_ROWCNT + NN*4u)
#define OFF_CSCALE   (OFF_RSCALE + NN*4u)
#define OFF_CSR      (OFF_CSCALE + NE*4u)              // [NN][RCAP] u32 = 4 MB
#define OFF_CSC      (OFF_CSR + NN*RCAP*4u)            // [NE][CCAP] u32 = 6 MB
#define OFF_Y0       (OFF_CSC + NE*CCAP*4u)            // [NN][64]  f32, pre-scaled by rscale
#define OFF_X1PRE    (OFF_Y0 + NN*64*4u)               // [NE][64]  f32
#define OFF_Z1       (OFF_X1PRE + NE*64*4u)            // [NE][64]  f32, pre-scaled by cscale

// One block per row: single coalesced float4 pass over B1, building CSR + CSC
// buckets directly. Row cursor in LDS, col cursor global atomic.
__global__ __launch_bounds__(256) void k_scan(const float* __restrict__ B1,
        uint32_t* __restrict__ row_cnt, uint32_t* __restrict__ col_cnt,
        uint32_t* __restrict__ csr_col, uint32_t* __restrict__ csc_row) {
    __shared__ uint32_t rcur;
    const int tid = threadIdx.x;
    const int i = blockIdx.x;
    if (tid == 0) rcur = 0;
    __syncthreads();
    const long long base = (long long)i * NE;
    for (int it = 0; it < 16; ++it) {
        int local = it * 1024 + tid * 4;        // 0..16383
        float4 v = *reinterpret_cast<const float4*>(B1 + base + local);
        float vs[4] = {v.x, v.y, v.z, v.w};
        #pragma unroll
        for (int q = 0; q < 4; ++q) {
            if (vs[q] != 0.0f) {
                uint32_t j = (uint32_t)(local + q);
                uint32_t p = atomicAdd(&rcur, 1u);
                if (p < RCAP) csr_col[(uint32_t)i * RCAP + p] = j;
                uint32_t qq = atomicAdd(&col_cnt[j], 1u);
                if (qq < CCAP) csc_row[j * CCAP + qq] = (uint32_t)i;
            }
        }
    }
    __syncthreads();
    if (tid == 0) row_cnt[i] = (rcur < RCAP) ? rcur : RCAP;
}

// One wave per row (units 0..NN-1) or col (units NN..NN+NE-1); norms computed
// on the fly from counts: enorm[j]=c^-1.5, nnorm[i]=c^-0.5.
// rowscale[i] = nnorm[i] / sum_j enorm[j];  colscale[j] = enorm[j] / sum_i nnorm[i]
__global__ __launch_bounds__(256) void k_scales(
        const uint32_t* __restrict__ row_cnt, const uint32_t* __restrict__ col_cnt,
        const uint32_t* __restrict__ csr_col, const uint32_t* __restrict__ csc_row,
        float* __restrict__ rowscale, float* __restrict__ colscale) {
    int w = blockIdx.x * 4 + (threadIdx.x >> 6);
    int lane = threadIdx.x & 63;
    float s = 0.f;
    if (w < NN) {
        uint32_t c = row_cnt[w];
        const uint32_t* p = csr_col + (uint32_t)w * RCAP;
        for (uint32_t t = lane; t < c; t += 64) {
            float cj = (float)col_cnt[p[t]];
            s += 1.0f / (cj * sqrtf(cj));
        }
        #pragma unroll
        for (int off = 32; off >= 1; off >>= 1) s += __shfl_xor(s, off);
        if (lane == 0) rowscale[w] = 1.0f / (sqrtf((float)c) * s);
    } else {
        int j = w - NN;
        uint32_t c = col_cnt[j];
        uint32_t cl = c > CCAP ? CCAP : c;
        const uint32_t* p = csc_row + (uint32_t)j * CCAP;
        for (uint32_t t = lane; t < cl; t += 64) {
            float ri = (float)row_cnt[p[t]];
            s += 1.0f / sqrtf(ri);
        }
        #pragma unroll
        for (int off = 32; off >= 1; off >>= 1) s += __shfl_xor(s, off);
        float cf = (float)c;
        if (lane == 0) colscale[j] = 1.0f / (cf * sqrtf(cf) * s);
    }
}

// Y[r,:] = scale[r] * (X[r,:] @ W);  block = 4 rows x 64 cols
__global__ __launch_bounds__(256) void k_gemm64(const float* __restrict__ X,
        const float* __restrict__ W, const float* __restrict__ scale,
        float* __restrict__ Y) {
    __shared__ float ws[64 * 64];
    __shared__ float xs[4][64];
    int tid = threadIdx.x;
    int c = tid & 63, rr = tid >> 6;
    for (int k = tid; k < 4096; k += 256) ws[k] = W[k];
    int row0 = blockIdx.x * 4;
    xs[rr][c] = X[(row0 + rr) * 64 + c];
    __syncthreads();
    float acc = 0.f;
    #pragma unroll
    for (int k = 0; k < 64; ++k) acc = fmaf(xs[rr][k], ws[k * 64 + c], acc);
    Y[(row0 + rr) * 64 + c] = scale[row0 + rr] * acc;
}

// x1[j,:] = colscale[j] * sum_{i in col j} y0s[i,:] + b01  (y0s pre-scaled by rowscale)
// Wave = 4 groups of 16 lanes; group g reads neighbor t+g's full row as float4.
__global__ __launch_bounds__(256) void k_edge_gather(
        const uint32_t* __restrict__ col_cnt, const uint32_t* __restrict__ csc_row,
        const float* __restrict__ colscale, const float* __restrict__ y0s,
        const float* __restrict__ bias01, float* __restrict__ x1pre,
        float* __restrict__ out1) {
    int w = threadIdx.x >> 6, lane = threadIdx.x & 63;
    int j = blockIdx.x * 4 + w;
    uint32_t e = col_cnt[j]; if (e > CCAP) e = CCAP;
    const uint32_t* p = csc_row + (uint32_t)j * CCAP;
    int g = lane >> 4, fl = lane & 15;
    float4 acc = make_float4(0.f, 0.f, 0.f, 0.f);
    for (uint32_t t = g; t < e; t += 4) {
        uint32_t i = p[t];
        const float4 v = *reinterpret_cast<const float4*>(y0s + i * 64u + fl * 4);
        acc.x += v.x; acc.y += v.y; acc.z += v.z; acc.w += v.w;
    }
    acc.x += __shfl_xor(acc.x, 16); acc.y += __shfl_xor(acc.y, 16);
    acc.z += __shfl_xor(acc.z, 16); acc.w += __shfl_xor(acc.w, 16);
    acc.x += __shfl_xor(acc.x, 32); acc.y += __shfl_xor(acc.y, 32);
    acc.z += __shfl_xor(acc.z, 32); acc.w += __shfl_xor(acc.w, 32);
    if (g == 0) {
        float cs = colscale[j];
        const float4 bb = *reinterpret_cast<const float4*>(bias01 + fl * 4);
        float4 val = make_float4(fmaf(cs, acc.x, bb.x), fmaf(cs, acc.y, bb.y),
                                 fmaf(cs, acc.z, bb.z), fmaf(cs, acc.w, bb.w));
        *reinterpret_cast<float4*>(x1pre + j * 64u + fl * 4) = val;
        float4 r = make_float4(fmaxf(val.x, 0.f), fmaxf(val.y, 0.f),
                               fmaxf(val.z, 0.f), fmaxf(val.w, 0.f));
        *reinterpret_cast<float4*>(out1 + j * 64u + fl * 4) = r;
    }
}

// out0[i,:] = relu(rowscale[i] * sum_{j in row i} z1s[j,:] + b10)  (z1s pre-scaled by colscale)
__global__ __launch_bounds__(256) void k_node_gather(
        const uint32_t* __restrict__ row_cnt, const uint32_t* __restrict__ csr_col,
        const float* __restrict__ rowscale, const float* __restrict__ z1s,
        const float* __restrict__ bias10, float* __restrict__ out0) {
    int w = threadIdx.x >> 6, lane = threadIdx.x & 63;
    int i = blockIdx.x * 4 + w;
    uint32_t e = row_cnt[i];
    const uint32_t* p = csr_col + (uint32_t)i * RCAP;
    int g = lane >> 4, fl = lane & 15;
    float4 acc = make_float4(0.f, 0.f, 0.f, 0.f);
    for (uint32_t t = g; t < e; t += 4) {
        uint32_t jj = p[t];
        const float4 v = *reinterpret_cast<const float4*>(z1s + jj * 64u + fl * 4);
        acc.x += v.x; acc.y += v.y; acc.z += v.z; acc.w += v.w;
    }
    acc.x += __shfl_xor(acc.x, 16); acc.y += __shfl_xor(acc.y, 16);
    acc.z += __shfl_xor(acc.z, 16); acc.w += __shfl_xor(acc.w, 16);
    acc.x += __shfl_xor(acc.x, 32); acc.y += __shfl_xor(acc.y, 32);
    acc.z += __shfl_xor(acc.z, 32); acc.w += __shfl_xor(acc.w, 32);
    if (g == 0) {
        float rs = rowscale[i];
        const float4 bb = *reinterpret_cast<const float4*>(bias10 + fl * 4);
        float4 val = make_float4(fmaf(rs, acc.x, bb.x), fmaf(rs, acc.y, bb.y),
                                 fmaf(rs, acc.z, bb.z), fmaf(rs, acc.w, bb.w));
        float4 r = make_float4(fmaxf(val.x, 0.f), fmaxf(val.y, 0.f),
                               fmaxf(val.z, 0.f), fmaxf(val.w, 0.f));
        *reinterpret_cast<float4*>(out0 + i * 64u + fl * 4) = r;
    }
}

extern "C" void kernel_launch(void* const* d_in, const int* in_sizes, int n_in,
                              void* d_out, int out_size, void* d_ws, size_t ws_size,
                              hipStream_t stream) {
    const float* x0  = (const float*)d_in[0];
    const float* B1  = (const float*)d_in[1];
    const float* W0  = (const float*)d_in[2];
    const float* W1  = (const float*)d_in[3];
    const float* b01 = (const float*)d_in[4];
    const float* b10 = (const float*)d_in[5];
    float* out = (float*)d_out;
    char* ws = (char*)d_ws;

    uint32_t* col_cnt = (uint32_t*)(ws + OFF_COLCNT);
    uint32_t* row_cnt = (uint32_t*)(ws + OFF_ROWCNT);
    float*    rscale  = (float*)(ws + OFF_RSCALE);
    float*    cscale  = (float*)(ws + OFF_CSCALE);
    uint32_t* csr_col = (uint32_t*)(ws + OFF_CSR);
    uint32_t* csc_row = (uint32_t*)(ws + OFF_CSC);
    float*    y0      = (float*)(ws + OFF_Y0);
    float*    x1pre   = (float*)(ws + OFF_X1PRE);
    float*    z1      = (float*)(ws + OFF_Z1);

    hipMemsetAsync(col_cnt, 0, MEMSET_BYTES, stream);

    k_scan<<<NN, 256, 0, stream>>>(B1, row_cnt, col_cnt, csr_col, csc_row);
    k_scales<<<(NN + NE) / 4, 256, 0, stream>>>(row_cnt, col_cnt, csr_col, csc_row,
            rscale, cscale);
    k_gemm64<<<NN / 4, 256, 0, stream>>>(x0, W0, rscale, y0);
    k_edge_gather<<<NE / 4, 256, 0, stream>>>(col_cnt, csc_row, cscale, y0,
            b01, x1pre, out + NN * 64);
    k_gemm64<<<NE / 4, 256, 0, stream>>>(x1pre, W1, cscale, z1);
    k_node_gather<<<NN / 4, 256, 0, stream>>>(row_cnt, csr_col, rscale, z1, b10, out);
}

// Round 4
// 757.829 us; speedup vs baseline: 1.3579x; 1.0119x over previous
//
#include <hip/hip_runtime.h>
#include <hip/hip_bf16.h>
#include <stdint.h>

#define NN 8192      // nodes
#define NE 16384     // hyperedges
#define RCAP 128     // max row degree bucket (Poisson lambda~67)
#define CCAP 96      // max col degree bucket (Poisson lambda~34)

typedef float f32x4 __attribute__((ext_vector_type(4)));

// ---------------- workspace layout (bytes) ----------------
#define OFF_COLCNT   0u
#define MEMSET_BYTES (NE*4u)                           // only col_cnt needs zeroing
#define OFF_ROWCNT   MEMSET_BYTES
#define OFF_RSCALE   (OFF_ROWCNT + NN*4u)
#define OFF_CSCALE   (OFF_RSCALE + NN*4u)
#define OFF_CSR      (OFF_CSCALE + NE*4u)              // [NN][RCAP] u32 = 4 MB
#define OFF_CSC      (OFF_CSR + NN*RCAP*4u)            // [NE][CCAP] u32 = 6 MB
#define OFF_Y0       (OFF_CSC + NE*CCAP*4u)            // [NN][64]  f32 (scaled in-place by K_B)
#define OFF_Z1       (OFF_Y0 + NN*64*4u)               // [NE][64]  f32, pre-scaled by cscale

// K_A: blocks 0..NN-1 scan one B1 row each (CSR+CSC build);
//      blocks NN..NN+NN/4-1 compute y0 = x0 @ W0 (unscaled) — rides free under BW.
__global__ __launch_bounds__(256) void k_scan_gemm(const float* __restrict__ B1,
        const float* __restrict__ x0, const float* __restrict__ W0,
        uint32_t* __restrict__ row_cnt, uint32_t* __restrict__ col_cnt,
        uint32_t* __restrict__ csr_col, uint32_t* __restrict__ csc_row,
        float* __restrict__ y0) {
    __shared__ float wsm[64 * 64];
    __shared__ float xs[4][64];
    __shared__ uint32_t rcur;
    const int tid = threadIdx.x;
    if (blockIdx.x < NN) {
        const int i = blockIdx.x;
        if (tid == 0) rcur = 0;
        __syncthreads();
        const long long base = (long long)i * NE;
        for (int it = 0; it < 16; ++it) {
            int local = it * 1024 + tid * 4;        // 0..16383
            f32x4 v = __builtin_nontemporal_load(
                    reinterpret_cast<const f32x4*>(B1 + base + local));
            #pragma unroll
            for (int q = 0; q < 4; ++q) {
                if (v[q] != 0.0f) {
                    uint32_t j = (uint32_t)(local + q);
                    uint32_t p = atomicAdd(&rcur, 1u);
                    if (p < RCAP) csr_col[(uint32_t)i * RCAP + p] = j;
                    uint32_t qq = atomicAdd(&col_cnt[j], 1u);
                    if (qq < CCAP) csc_row[j * CCAP + qq] = (uint32_t)i;
                }
            }
        }
        __syncthreads();
        if (tid == 0) row_cnt[i] = (rcur < RCAP) ? rcur : RCAP;
    } else {
        int c = tid & 63, rr = tid >> 6;
        for (int k = tid * 4; k < 4096; k += 1024)
            *reinterpret_cast<f32x4*>(wsm + k) =
                *reinterpret_cast<const f32x4*>(W0 + k);
        int row0 = (blockIdx.x - NN) * 4;
        xs[rr][c] = x0[(row0 + rr) * 64 + c];
        __syncthreads();
        float acc = 0.f;
        #pragma unroll
        for (int k = 0; k < 64; ++k) acc = fmaf(xs[rr][k], wsm[k * 64 + c], acc);
        y0[(row0 + rr) * 64 + c] = acc;
    }
}

// K_B: one wave per row (w<NN) or col (w>=NN). Norms from counts on the fly.
// Row wave: rowscale[i] = nnorm/sum(enorm of neighbors); scales y0 row in place.
// Col wave: colscale[j] stored (applied to z1 in K_C).
__global__ __launch_bounds__(256) void k_scales(
        const uint32_t* __restrict__ row_cnt, const uint32_t* __restrict__ col_cnt,
        const uint32_t* __restrict__ csr_col, const uint32_t* __restrict__ csc_row,
        float* __restrict__ rowscale, float* __restrict__ colscale,
        float* __restrict__ y0) {
    int w = blockIdx.x * 4 + (threadIdx.x >> 6);
    int lane = threadIdx.x & 63;
    float s = 0.f;
    if (w < NN) {
        uint32_t c = row_cnt[w];
        const uint32_t* p = csr_col + (uint32_t)w * RCAP;
        for (uint32_t t = lane; t < c; t += 64) {
            float cj = (float)col_cnt[p[t]];
            s += 1.0f / (cj * sqrtf(cj));
        }
        #pragma unroll
        for (int off = 32; off >= 1; off >>= 1) s += __shfl_xor(s, off);
        float rs = 1.0f / (sqrtf((float)c) * s);
        y0[w * 64 + lane] *= rs;
        if (lane == 0) rowscale[w] = rs;
    } else {
        int j = w - NN;
        uint32_t c = col_cnt[j];
        uint32_t cl = c > CCAP ? CCAP : c;
        const uint32_t* p = csc_row + (uint32_t)j * CCAP;
        for (uint32_t t = lane; t < cl; t += 64) {
            float ri = (float)row_cnt[p[t]];
            s += 1.0f / sqrtf(ri);
        }
        #pragma unroll
        for (int off = 32; off >= 1; off >>= 1) s += __shfl_xor(s, off);
        float cf = (float)c;
        if (lane == 0) colscale[j] = 1.0f / (cf * sqrtf(cf) * s);
    }
}

// K_C: per edge j (4 edges/block): x1row = sum_{i in col j} y0s[i,:] (4x16 float4
// gather + shfl), then val = colscale*x1row + b01 -> LDS; out1 = relu(val);
// then block-level 64x64 GEMM: z1[j,:] = colscale[j]... wait, z1 = cscale*(x1 @ W1)?
// No: z1[j,:] = cscale-scaled? Careful: x1 already includes cscale+bias; z1 needs
// colscale[j] applied to the NODE-side pass, i.e. z1s[j,:] = colscale[j]*(x1[j,:]@W1).
__global__ __launch_bounds__(256) void k_edge_fused(
        const uint32_t* __restrict__ col_cnt, const uint32_t* __restrict__ csc_row,
        const float* __restrict__ colscale, const float* __restrict__ y0s,
        const float* __restrict__ bias01, const float* __restrict__ W1,
        float* __restrict__ z1s, float* __restrict__ out1) {
    __shared__ float w1s[64 * 64];
    __shared__ float xrow[4][64];
    int tid = threadIdx.x;
    for (int k = tid * 4; k < 4096; k += 1024)
        *reinterpret_cast<f32x4*>(w1s + k) =
            *reinterpret_cast<const f32x4*>(W1 + k);
    int w = tid >> 6, lane = tid & 63;
    int j = blockIdx.x * 4 + w;
    uint32_t e = col_cnt[j]; if (e > CCAP) e = CCAP;
    const uint32_t* p = csc_row + (uint32_t)j * CCAP;
    int g = lane >> 4, fl = lane & 15;
    float4 acc = make_float4(0.f, 0.f, 0.f, 0.f);
    for (uint32_t t = g; t < e; t += 4) {
        uint32_t i = p[t];
        const float4 v = *reinterpret_cast<const float4*>(y0s + i * 64u + fl * 4);
        acc.x += v.x; acc.y += v.y; acc.z += v.z; acc.w += v.w;
    }
    acc.x += __shfl_xor(acc.x, 16); acc.y += __shfl_xor(acc.y, 16);
    acc.z += __shfl_xor(acc.z, 16); acc.w += __shfl_xor(acc.w, 16);
    acc.x += __shfl_xor(acc.x, 32); acc.y += __shfl_xor(acc.y, 32);
    acc.z += __shfl_xor(acc.z, 32); acc.w += __shfl_xor(acc.w, 32);
    if (g == 0) {
        float cs = colscale[j];
        const float4 bb = *reinterpret_cast<const float4*>(bias01 + fl * 4);
        float4 val = make_float4(fmaf(cs, acc.x, bb.x), fmaf(cs, acc.y, bb.y),
                                 fmaf(cs, acc.z, bb.z), fmaf(cs, acc.w, bb.w));
        *reinterpret_cast<float4*>(&xrow[w][fl * 4]) = val;
        float4 r = make_float4(fmaxf(val.x, 0.f), fmaxf(val.y, 0.f),
                               fmaxf(val.z, 0.f), fmaxf(val.w, 0.f));
        *reinterpret_cast<float4*>(out1 + j * 64u + fl * 4) = r;
    }
    __syncthreads();
    // z1s[j,:] = colscale[j] * (xrow[w] @ W1)
    float z = 0.f;
    #pragma unroll
    for (int k = 0; k < 64; ++k) z = fmaf(xrow[w][k], w1s[k * 64 + lane], z);
    z1s[j * 64 + lane] = colscale[j] * z;
}

// K_D: out0[i,:] = relu(rowscale[i] * sum_{j in row i} z1s[j,:] + b10)
__global__ __launch_bounds__(256) void k_node_gather(
        const uint32_t* __restrict__ row_cnt, const uint32_t* __restrict__ csr_col,
        const float* __restrict__ rowscale, const float* __restrict__ z1s,
        const float* __restrict__ bias10, float* __restrict__ out0) {
    int w = threadIdx.x >> 6, lane = threadIdx.x & 63;
    int i = blockIdx.x * 4 + w;
    uint32_t e = row_cnt[i];
    const uint32_t* p = csr_col + (uint32_t)i * RCAP;
    int g = lane >> 4, fl = lane & 15;
    float4 acc = make_float4(0.f, 0.f, 0.f, 0.f);
    for (uint32_t t = g; t < e; t += 4) {
        uint32_t jj = p[t];
        const float4 v = *reinterpret_cast<const float4*>(z1s + jj * 64u + fl * 4);
        acc.x += v.x; acc.y += v.y; acc.z += v.z; acc.w += v.w;
    }
    acc.x += __shfl_xor(acc.x, 16); acc.y += __shfl_xor(acc.y, 16);
    acc.z += __shfl_xor(acc.z, 16); acc.w += __shfl_xor(acc.w, 16);
    acc.x += __shfl_xor(acc.x, 32); acc.y += __shfl_xor(acc.y, 32);
    acc.z += __shfl_xor(acc.z, 32); acc.w += __shfl_xor(acc.w, 32);
    if (g == 0) {
        float rs = rowscale[i];
        const float4 bb = *reinterpret_cast<const float4*>(bias10 + fl * 4);
        float4 r = make_float4(fmaxf(fmaf(rs, acc.x, bb.x), 0.f),
                               fmaxf(fmaf(rs, acc.y, bb.y), 0.f),
                               fmaxf(fmaf(rs, acc.z, bb.z), 0.f),
                               fmaxf(fmaf(rs, acc.w, bb.w), 0.f));
        *reinterpret_cast<float4*>(out0 + i * 64u + fl * 4) = r;
    }
}

extern "C" void kernel_launch(void* const* d_in, const int* in_sizes, int n_in,
                              void* d_out, int out_size, void* d_ws, size_t ws_size,
                              hipStream_t stream) {
    const float* x0  = (const float*)d_in[0];
    const float* B1  = (const float*)d_in[1];
    const float* W0  = (const float*)d_in[2];
    const float* W1  = (const float*)d_in[3];
    const float* b01 = (const float*)d_in[4];
    const float* b10 = (const float*)d_in[5];
    float* out = (float*)d_out;
    char* ws = (char*)d_ws;

    uint32_t* col_cnt = (uint32_t*)(ws + OFF_COLCNT);
    uint32_t* row_cnt = (uint32_t*)(ws + OFF_ROWCNT);
    float*    rscale  = (float*)(ws + OFF_RSCALE);
    float*    cscale  = (float*)(ws + OFF_CSCALE);
    uint32_t* csr_col = (uint32_t*)(ws + OFF_CSR);
    uint32_t* csc_row = (uint32_t*)(ws + OFF_CSC);
    float*    y0      = (float*)(ws + OFF_Y0);
    float*    z1      = (float*)(ws + OFF_Z1);

    hipMemsetAsync(col_cnt, 0, MEMSET_BYTES, stream);

    k_scan_gemm<<<NN + NN / 4, 256, 0, stream>>>(B1, x0, W0, row_cnt, col_cnt,
            csr_col, csc_row, y0);
    k_scales<<<(NN + NE) / 4, 256, 0, stream>>>(row_cnt, col_cnt, csr_col, csc_row,
            rscale, cscale, y0);
    k_edge_fused<<<NE / 4, 256, 0, stream>>>(col_cnt, csc_row, cscale, y0,
            b01, W1, z1, out + NN * 64);
    k_node_gather<<<NN / 4, 256, 0, stream>>>(row_cnt, csr_col, rscale, z1, b10, out);
}

// Round 6
// 753.313 us; speedup vs baseline: 1.3661x; 1.0060x over previous
//
#include <hip/hip_runtime.h>
#include <hip/hip_bf16.h>
#include <stdint.h>

#define NN 8192      // nodes
#define NE 16384     // hyperedges
#define RCAP 128     // max row degree bucket (Poisson lambda~67)
#define CCAP 96      // max col degree bucket (Poisson lambda~34)

typedef float f32x4 __attribute__((ext_vector_type(4)));

// ---------------- workspace layout (bytes) ----------------
#define OFF_COLCNT   0u
#define MEMSET_BYTES (NE*4u)                           // only col_cnt needs zeroing
#define OFF_ROWCNT   MEMSET_BYTES
#define OFF_RSCALE   (OFF_ROWCNT + NN*4u)
#define OFF_CSR      (OFF_RSCALE + NN*4u)              // [NN][RCAP] u32 = 4 MB
#define OFF_CSC      (OFF_CSR + NN*RCAP*4u)            // [NE][CCAP] u32 = 6 MB
#define OFF_Y0       (OFF_CSC + NE*CCAP*4u)            // [NN][64] f32 (scaled in place)
#define OFF_Z1       (OFF_Y0 + NN*64*4u)               // [NE][64] f32, pre-scaled by colscale

// K_A: blocks 0..NN-1 scan one B1 row each (CSR+CSC build);
//      blocks NN.. compute y0 = x0 @ W0 (unscaled) — rides free under the B1 stream.
__global__ __launch_bounds__(256) void k_scan_gemm(const float* __restrict__ B1,
        const float* __restrict__ x0, const float* __restrict__ W0,
        uint32_t* __restrict__ row_cnt, uint32_t* __restrict__ col_cnt,
        uint32_t* __restrict__ csr_col, uint32_t* __restrict__ csc_row,
        float* __restrict__ y0) {
    __shared__ float wsm[64 * 64];
    __shared__ float xs[4][64];
    __shared__ uint32_t rcur;
    const int tid = threadIdx.x;
    if (blockIdx.x < NN) {
        const int i = blockIdx.x;
        if (tid == 0) rcur = 0;
        __syncthreads();
        const long long base = (long long)i * NE;
        for (int it = 0; it < 16; ++it) {
            int local = it * 1024 + tid * 4;        // 0..16383
            f32x4 v = __builtin_nontemporal_load(
                    reinterpret_cast<const f32x4*>(B1 + base + local));
            #pragma unroll
            for (int q = 0; q < 4; ++q) {
                if (v[q] != 0.0f) {
                    uint32_t j = (uint32_t)(local + q);
                    uint32_t p = atomicAdd(&rcur, 1u);
                    if (p < RCAP) csr_col[(uint32_t)i * RCAP + p] = j;
                    uint32_t qq = atomicAdd(&col_cnt[j], 1u);
                    if (qq < CCAP) csc_row[j * CCAP + qq] = (uint32_t)i;
                }
            }
        }
        __syncthreads();
        if (tid == 0) row_cnt[i] = rcur;            // true count (clamp at use sites)
    } else {
        int c = tid & 63, rr = tid >> 6;
        for (int k = tid * 4; k < 4096; k += 1024)
            *reinterpret_cast<f32x4*>(wsm + k) =
                *reinterpret_cast<const f32x4*>(W0 + k);
        int row0 = (blockIdx.x - NN) * 4;
        xs[rr][c] = x0[(row0 + rr) * 64 + c];
        __syncthreads();
        float acc = 0.f;
        #pragma unroll
        for (int k = 0; k < 64; ++k) acc = fmaf(xs[rr][k], wsm[k * 64 + c], acc);
        y0[(row0 + rr) * 64 + c] = acc;
    }
}

// K_B: one wave per node row. rscale[i] = nnorm[i]/sum_{j in row} enorm[j];
// scales y0 row in place so the edge gather is a pure sum.
__global__ __launch_bounds__(256) void k_rowscale(
        const uint32_t* __restrict__ row_cnt, const uint32_t* __restrict__ col_cnt,
        const uint32_t* __restrict__ csr_col,
        float* __restrict__ rowscale, float* __restrict__ y0) {
    int i = blockIdx.x * 4 + (threadIdx.x >> 6);
    int lane = threadIdx.x & 63;
    uint32_t c = row_cnt[i];
    uint32_t cl = c > RCAP ? RCAP : c;
    const uint32_t* p = csr_col + (uint32_t)i * RCAP;
    float s = 0.f;
    for (uint32_t t = lane; t < cl; t += 64) {
        float cj = (float)col_cnt[p[t]];
        s += 1.0f / (cj * sqrtf(cj));
    }
    #pragma unroll
    for (int off = 32; off >= 1; off >>= 1) s += __shfl_xor(s, off);
    float rs = 1.0f / (sqrtf((float)c) * s);
    y0[i * 64 + lane] *= rs;
    if (lane == 0) rowscale[i] = rs;
}

// K_C: per edge j (4/block): gather x1row = sum_{i in col j} y0s[i,:] with
// prefetched indices (u0/u1) + WAVE-UNIFORM trip count (all lanes run every
// iteration so __shfl source lanes are always active; loads guarded by t<e).
// On-the-fly colscale (fl==0 lanes accumulate 1/sqrt(row_cnt)), relu->out1,
// then block 64x64 GEMM: z1s = colscale*(x1@W1).
__global__ __launch_bounds__(256) void k_edge_fused(
        const uint32_t* __restrict__ col_cnt, const uint32_t* __restrict__ csc_row,
        const uint32_t* __restrict__ row_cnt, const float* __restrict__ y0s,
        const float* __restrict__ bias01, const float* __restrict__ W1,
        float* __restrict__ z1s, float* __restrict__ out1) {
    __shared__ float w1s[64 * 64];
    __shared__ float xrow[4][64];
    __shared__ float csh[4];
    int tid = threadIdx.x;
    for (int k = tid * 4; k < 4096; k += 1024)
        *reinterpret_cast<f32x4*>(w1s + k) =
            *reinterpret_cast<const f32x4*>(W1 + k);
    int w = tid >> 6, lane = tid & 63;
    int j = blockIdx.x * 4 + w;
    uint32_t c = col_cnt[j];
    uint32_t e = c > CCAP ? CCAP : c;
    const uint32_t* p = csc_row + (uint32_t)j * CCAP;
    uint32_t u0 = p[lane];                  // indices 0..63 (tail lanes: unused garbage)
    uint32_t u1 = p[64 + lane];             // indices 64..95 (lanes >=32 unused)
    int g = lane >> 4, fl = lane & 15;
    float4 acc = make_float4(0.f, 0.f, 0.f, 0.f);
    float ns = 0.f;
    uint32_t niter = (e + 3u) >> 2;         // uniform across the wave
    for (uint32_t k = 0; k < niter; ++k) {
        uint32_t t = g + 4u * k;
        // t's 4-block never straddles 64 -> ternary is wave-uniform; all lanes
        // execute the shfl, so every source lane is active.
        uint32_t idx = (t < 64u) ? (uint32_t)__shfl((int)u0, (int)t)
                                 : (uint32_t)__shfl((int)u1, (int)(t - 64u));
        if (t < e) {
            const float4 v = *reinterpret_cast<const float4*>(y0s + idx * 64u + fl * 4);
            if (fl == 0) ns += 1.0f / sqrtf((float)row_cnt[idx]);
            acc.x += v.x; acc.y += v.y; acc.z += v.z; acc.w += v.w;
        }
    }
    acc.x += __shfl_xor(acc.x, 16); acc.y += __shfl_xor(acc.y, 16);
    acc.z += __shfl_xor(acc.z, 16); acc.w += __shfl_xor(acc.w, 16);
    acc.x += __shfl_xor(acc.x, 32); acc.y += __shfl_xor(acc.y, 32);
    acc.z += __shfl_xor(acc.z, 32); acc.w += __shfl_xor(acc.w, 32);
    ns += __shfl_xor(ns, 16); ns += __shfl_xor(ns, 32);
    float cf = (float)c;
    float cs = __shfl(1.0f / (cf * sqrtf(cf) * ns), 0);   // colscale[j], broadcast
    if (g == 0) {
        const float4 bb = *reinterpret_cast<const float4*>(bias01 + fl * 4);
        float4 val = make_float4(fmaf(cs, acc.x, bb.x), fmaf(cs, acc.y, bb.y),
                                 fmaf(cs, acc.z, bb.z), fmaf(cs, acc.w, bb.w));
        *reinterpret_cast<float4*>(&xrow[w][fl * 4]) = val;
        float4 r = make_float4(fmaxf(val.x, 0.f), fmaxf(val.y, 0.f),
                               fmaxf(val.z, 0.f), fmaxf(val.w, 0.f));
        *reinterpret_cast<float4*>(out1 + j * 64u + fl * 4) = r;
        if (fl == 0) csh[w] = cs;
    }
    __syncthreads();
    float z = 0.f;
    #pragma unroll
    for (int k = 0; k < 64; ++k) z = fmaf(xrow[w][k], w1s[k * 64 + lane], z);
    z1s[j * 64 + lane] = csh[w] * z;
}

// K_D: out0[i,:] = relu(rowscale[i] * sum_{j in row i} z1s[j,:] + b10)
__global__ __launch_bounds__(256) void k_node_gather(
        const uint32_t* __restrict__ row_cnt, const uint32_t* __restrict__ csr_col,
        const float* __restrict__ rowscale, const float* __restrict__ z1s,
        const float* __restrict__ bias10, float* __restrict__ out0) {
    int w = threadIdx.x >> 6, lane = threadIdx.x & 63;
    int i = blockIdx.x * 4 + w;
    uint32_t c = row_cnt[i];
    uint32_t e = c > RCAP ? RCAP : c;
    const uint32_t* p = csr_col + (uint32_t)i * RCAP;
    uint32_t u0 = p[lane];
    uint32_t u1 = p[64 + lane];
    int g = lane >> 4, fl = lane & 15;
    float4 acc = make_float4(0.f, 0.f, 0.f, 0.f);
    uint32_t niter = (e + 3u) >> 2;         // uniform across the wave
    for (uint32_t k = 0; k < niter; ++k) {
        uint32_t t = g + 4u * k;
        uint32_t idx = (t < 64u) ? (uint32_t)__shfl((int)u0, (int)t)
                                 : (uint32_t)__shfl((int)u1, (int)(t - 64u));
        if (t < e) {
            const float4 v = *reinterpret_cast<const float4*>(z1s + idx * 64u + fl * 4);
            acc.x += v.x; acc.y += v.y; acc.z += v.z; acc.w += v.w;
        }
    }
    acc.x += __shfl_xor(acc.x, 16); acc.y += __shfl_xor(acc.y, 16);
    acc.z += __shfl_xor(acc.z, 16); acc.w += __shfl_xor(acc.w, 16);
    acc.x += __shfl_xor(acc.x, 32); acc.y += __shfl_xor(acc.y, 32);
    acc.z += __shfl_xor(acc.z, 32); acc.w += __shfl_xor(acc.w, 32);
    if (g == 0) {
        float rs = rowscale[i];
        const float4 bb = *reinterpret_cast<const float4*>(bias10 + fl * 4);
        float4 r = make_float4(fmaxf(fmaf(rs, acc.x, bb.x), 0.f),
                               fmaxf(fmaf(rs, acc.y, bb.y), 0.f),
                               fmaxf(fmaf(rs, acc.z, bb.z), 0.f),
                               fmaxf(fmaf(rs, acc.w, bb.w), 0.f));
        *reinterpret_cast<float4*>(out0 + i * 64u + fl * 4) = r;
    }
}

extern "C" void kernel_launch(void* const* d_in, const int* in_sizes, int n_in,
                              void* d_out, int out_size, void* d_ws, size_t ws_size,
                              hipStream_t stream) {
    const float* x0  = (const float*)d_in[0];
    const float* B1  = (const float*)d_in[1];
    const float* W0  = (const float*)d_in[2];
    const float* W1  = (const float*)d_in[3];
    const float* b01 = (const float*)d_in[4];
    const float* b10 = (const float*)d_in[5];
    float* out = (float*)d_out;
    char* ws = (char*)d_ws;

    uint32_t* col_cnt = (uint32_t*)(ws + OFF_COLCNT);
    uint32_t* row_cnt = (uint32_t*)(ws + OFF_ROWCNT);
    float*    rscale  = (float*)(ws + OFF_RSCALE);
    uint32_t* csr_col = (uint32_t*)(ws + OFF_CSR);
    uint32_t* csc_row = (uint32_t*)(ws + OFF_CSC);
    float*    y0      = (float*)(ws + OFF_Y0);
    float*    z1      = (float*)(ws + OFF_Z1);

    hipMemsetAsync(col_cnt, 0, MEMSET_BYTES, stream);

    k_scan_gemm<<<NN + NN / 4, 256, 0, stream>>>(B1, x0, W0, row_cnt, col_cnt,
            csr_col, csc_row, y0);
    k_rowscale<<<NN / 4, 256, 0, stream>>>(row_cnt, col_cnt, csr_col, rscale, y0);
    k_edge_fused<<<NE / 4, 256, 0, stream>>>(col_cnt, csc_row, row_cnt, y0,
            b01, W1, z1, out + NN * 64);
    k_node_gather<<<NN / 4, 256, 0, stream>>>(row_cnt, csr_col, rscale, z1, b10, out);
}

// Round 7
// 723.064 us; speedup vs baseline: 1.4232x; 1.0418x over previous
//
#include <hip/hip_runtime.h>
#include <hip/hip_bf16.h>
#include <stdint.h>

#define NN 8192      // nodes
#define NE 16384     // hyperedges
#define RCAP 128     // max row degree bucket (Poisson lambda~67)
#define CCAP 96      // max col degree bucket (Poisson lambda~34)

typedef float f32x4 __attribute__((ext_vector_type(4)));

// ---------------- workspace layout (bytes) ----------------
#define OFF_COLCNT   0u
#define MEMSET_BYTES (NE*4u)                           // only col_cnt needs zeroing
#define OFF_ROWCNT   MEMSET_BYTES
#define OFF_RSCALE   (OFF_ROWCNT + NN*4u)
#define OFF_CSR      (OFF_RSCALE + NN*4u)              // [NN][RCAP] u32 = 4 MB
#define OFF_CSC      (OFF_CSR + NN*RCAP*4u)            // [NE][CCAP] u32 = 6 MB
#define OFF_Y0       (OFF_CSC + NE*CCAP*4u)            // [NN][64] f32 (scaled in place)
#define OFF_Z1       (OFF_Y0 + NN*64*4u)               // [NE][64] f32, pre-scaled by colscale

// K_A: blocks 0..NN-1 scan one B1 row each. Two-phase: (A) stream the row with
// ONLY LDS-side effects (lgkmcnt — keeps the vmcnt load pipe warm; no global
// atomic-return drains), hits -> LDS list; (B) after the stream, lanes tid<cnt
// each emit one nonzero: csr store + ONE global atomic + csc scatter.
// Blocks NN.. compute y0 = x0 @ W0 (unscaled) — rides free under the B1 stream.
__global__ __launch_bounds__(256) void k_scan_gemm(const float* __restrict__ B1,
        const float* __restrict__ x0, const float* __restrict__ W0,
        uint32_t* __restrict__ row_cnt, uint32_t* __restrict__ col_cnt,
        uint32_t* __restrict__ csr_col, uint32_t* __restrict__ csc_row,
        float* __restrict__ y0) {
    __shared__ float wsm[64 * 64];
    __shared__ float xs[4][64];
    __shared__ uint32_t hits[RCAP];
    __shared__ uint32_t rcur;
    const int tid = threadIdx.x;
    if (blockIdx.x < NN) {
        const int i = blockIdx.x;
        if (tid == 0) rcur = 0;
        __syncthreads();
        const long long base = (long long)i * NE;
        for (int it = 0; it < 16; ++it) {
            int local = it * 1024 + tid * 4;        // 0..16383
            f32x4 v = *reinterpret_cast<const f32x4*>(B1 + base + local);
            #pragma unroll
            for (int q = 0; q < 4; ++q) {
                if (v[q] != 0.0f) {
                    uint32_t p = atomicAdd(&rcur, 1u);       // LDS atomic only
                    if (p < RCAP) hits[p] = (uint32_t)(local + q);
                }
            }
        }
        __syncthreads();
        uint32_t cnt = rcur;
        uint32_t cl = cnt > RCAP ? RCAP : cnt;
        if ((uint32_t)tid < cl) {
            uint32_t j = hits[tid];
            csr_col[(uint32_t)i * RCAP + tid] = j;
            uint32_t qq = atomicAdd(&col_cnt[j], 1u);        // one drain per row, batched
            if (qq < CCAP) csc_row[j * CCAP + qq] = (uint32_t)i;
        }
        if (tid == 0) row_cnt[i] = cnt;            // true count (clamp at use sites)
    } else {
        int c = tid & 63, rr = tid >> 6;
        for (int k = tid * 4; k < 4096; k += 1024)
            *reinterpret_cast<f32x4*>(wsm + k) =
                *reinterpret_cast<const f32x4*>(W0 + k);
        int row0 = (blockIdx.x - NN) * 4;
        xs[rr][c] = x0[(row0 + rr) * 64 + c];
        __syncthreads();
        float acc = 0.f;
        #pragma unroll
        for (int k = 0; k < 64; ++k) acc = fmaf(xs[rr][k], wsm[k * 64 + c], acc);
        y0[(row0 + rr) * 64 + c] = acc;
    }
}

// K_B: one wave per node row. rscale[i] = nnorm[i]/sum_{j in row} enorm[j];
// scales y0 row in place so the edge gather is a pure sum.
__global__ __launch_bounds__(256) void k_rowscale(
        const uint32_t* __restrict__ row_cnt, const uint32_t* __restrict__ col_cnt,
        const uint32_t* __restrict__ csr_col,
        float* __restrict__ rowscale, float* __restrict__ y0) {
    int i = blockIdx.x * 4 + (threadIdx.x >> 6);
    int lane = threadIdx.x & 63;
    uint32_t c = row_cnt[i];
    uint32_t cl = c > RCAP ? RCAP : c;
    const uint32_t* p = csr_col + (uint32_t)i * RCAP;
    float s = 0.f;
    for (uint32_t t = lane; t < cl; t += 64) {
        float cj = (float)col_cnt[p[t]];
        s += 1.0f / (cj * sqrtf(cj));
    }
    #pragma unroll
    for (int off = 32; off >= 1; off >>= 1) s += __shfl_xor(s, off);
    float rs = 1.0f / (sqrtf((float)c) * s);
    y0[i * 64 + lane] *= rs;
    if (lane == 0) rowscale[i] = rs;
}

// K_C: per edge j (4/block): gather x1row = sum_{i in col j} y0s[i,:] with
// prefetched indices (u0/u1) + wave-uniform trip count (all lanes run every
// iteration so __shfl source lanes are always active; loads guarded by t<e).
// On-the-fly colscale (fl==0 lanes accumulate 1/sqrt(row_cnt)), relu->out1,
// then block 64x64 GEMM: z1s = colscale*(x1@W1).
__global__ __launch_bounds__(256) void k_edge_fused(
        const uint32_t* __restrict__ col_cnt, const uint32_t* __restrict__ csc_row,
        const uint32_t* __restrict__ row_cnt, const float* __restrict__ y0s,
        const float* __restrict__ bias01, const float* __restrict__ W1,
        float* __restrict__ z1s, float* __restrict__ out1) {
    __shared__ float w1s[64 * 64];
    __shared__ float xrow[4][64];
    __shared__ float csh[4];
    int tid = threadIdx.x;
    for (int k = tid * 4; k < 4096; k += 1024)
        *reinterpret_cast<f32x4*>(w1s + k) =
            *reinterpret_cast<const f32x4*>(W1 + k);
    int w = tid >> 6, lane = tid & 63;
    int j = blockIdx.x * 4 + w;
    uint32_t c = col_cnt[j];
    uint32_t e = c > CCAP ? CCAP : c;
    const uint32_t* p = csc_row + (uint32_t)j * CCAP;
    uint32_t u0 = p[lane];                  // indices 0..63 (tail lanes: unused garbage)
    uint32_t u1 = p[64 + lane];             // indices 64..95 (lanes >=32 unused)
    int g = lane >> 4, fl = lane & 15;
    float4 acc = make_float4(0.f, 0.f, 0.f, 0.f);
    float ns = 0.f;
    uint32_t niter = (e + 3u) >> 2;         // uniform across the wave
    for (uint32_t k = 0; k < niter; ++k) {
        uint32_t t = g + 4u * k;
        uint32_t idx = (t < 64u) ? (uint32_t)__shfl((int)u0, (int)t)
                                 : (uint32_t)__shfl((int)u1, (int)(t - 64u));
        if (t < e) {
            const float4 v = *reinterpret_cast<const float4*>(y0s + idx * 64u + fl * 4);
            if (fl == 0) ns += 1.0f / sqrtf((float)row_cnt[idx]);
            acc.x += v.x; acc.y += v.y; acc.z += v.z; acc.w += v.w;
        }
    }
    acc.x += __shfl_xor(acc.x, 16); acc.y += __shfl_xor(acc.y, 16);
    acc.z += __shfl_xor(acc.z, 16); acc.w += __shfl_xor(acc.w, 16);
    acc.x += __shfl_xor(acc.x, 32); acc.y += __shfl_xor(acc.y, 32);
    acc.z += __shfl_xor(acc.z, 32); acc.w += __shfl_xor(acc.w, 32);
    ns += __shfl_xor(ns, 16); ns += __shfl_xor(ns, 32);
    float cf = (float)c;
    float cs = __shfl(1.0f / (cf * sqrtf(cf) * ns), 0);   // colscale[j], broadcast
    if (g == 0) {
        const float4 bb = *reinterpret_cast<const float4*>(bias01 + fl * 4);
        float4 val = make_float4(fmaf(cs, acc.x, bb.x), fmaf(cs, acc.y, bb.y),
                                 fmaf(cs, acc.z, bb.z), fmaf(cs, acc.w, bb.w));
        *reinterpret_cast<float4*>(&xrow[w][fl * 4]) = val;
        float4 r = make_float4(fmaxf(val.x, 0.f), fmaxf(val.y, 0.f),
                               fmaxf(val.z, 0.f), fmaxf(val.w, 0.f));
        *reinterpret_cast<float4*>(out1 + j * 64u + fl * 4) = r;
        if (fl == 0) csh[w] = cs;
    }
    __syncthreads();
    float z = 0.f;
    #pragma unroll
    for (int k = 0; k < 64; ++k) z = fmaf(xrow[w][k], w1s[k * 64 + lane], z);
    z1s[j * 64 + lane] = csh[w] * z;
}

// K_D: out0[i,:] = relu(rowscale[i] * sum_{j in row i} z1s[j,:] + b10)
__global__ __launch_bounds__(256) void k_node_gather(
        const uint32_t* __restrict__ row_cnt, const uint32_t* __restrict__ csr_col,
        const float* __restrict__ rowscale, const float* __restrict__ z1s,
        const float* __restrict__ bias10, float* __restrict__ out0) {
    int w = threadIdx.x >> 6, lane = threadIdx.x & 63;
    int i = blockIdx.x * 4 + w;
    uint32_t c = row_cnt[i];
    uint32_t e = c > RCAP ? RCAP : c;
    const uint32_t* p = csr_col + (uint32_t)i * RCAP;
    uint32_t u0 = p[lane];
    uint32_t u1 = p[64 + lane];
    int g = lane >> 4, fl = lane & 15;
    float4 acc = make_float4(0.f, 0.f, 0.f, 0.f);
    uint32_t niter = (e + 3u) >> 2;         // uniform across the wave
    for (uint32_t k = 0; k < niter; ++k) {
        uint32_t t = g + 4u * k;
        uint32_t idx = (t < 64u) ? (uint32_t)__shfl((int)u0, (int)t)
                                 : (uint32_t)__shfl((int)u1, (int)(t - 64u));
        if (t < e) {
            const float4 v = *reinterpret_cast<const float4*>(z1s + idx * 64u + fl * 4);
            acc.x += v.x; acc.y += v.y; acc.z += v.z; acc.w += v.w;
        }
    }
    acc.x += __shfl_xor(acc.x, 16); acc.y += __shfl_xor(acc.y, 16);
    acc.z += __shfl_xor(acc.z, 16); acc.w += __shfl_xor(acc.w, 16);
    acc.x += __shfl_xor(acc.x, 32); acc.y += __shfl_xor(acc.y, 32);
    acc.z += __shfl_xor(acc.z, 32); acc.w += __shfl_xor(acc.w, 32);
    if (g == 0) {
        float rs = rowscale[i];
        const float4 bb = *reinterpret_cast<const float4*>(bias10 + fl * 4);
        float4 r = make_float4(fmaxf(fmaf(rs, acc.x, bb.x), 0.f),
                               fmaxf(fmaf(rs, acc.y, bb.y), 0.f),
                               fmaxf(fmaf(rs, acc.z, bb.z), 0.f),
                               fmaxf(fmaf(rs, acc.w, bb.w), 0.f));
        *reinterpret_cast<float4*>(out0 + i * 64u + fl * 4) = r;
    }
}

extern "C" void kernel_launch(void* const* d_in, const int* in_sizes, int n_in,
                              void* d_out, int out_size, void* d_ws, size_t ws_size,
                              hipStream_t stream) {
    const float* x0  = (const float*)d_in[0];
    const float* B1  = (const float*)d_in[1];
    const float* W0  = (const float*)d_in[2];
    const float* W1  = (const float*)d_in[3];
    const float* b01 = (const float*)d_in[4];
    const float* b10 = (const float*)d_in[5];
    float* out = (float*)d_out;
    char* ws = (char*)d_ws;

    uint32_t* col_cnt = (uint32_t*)(ws + OFF_COLCNT);
    uint32_t* row_cnt = (uint32_t*)(ws + OFF_ROWCNT);
    float*    rscale  = (float*)(ws + OFF_RSCALE);
    uint32_t* csr_col = (uint32_t*)(ws + OFF_CSR);
    uint32_t* csc_row = (uint32_t*)(ws + OFF_CSC);
    float*    y0      = (float*)(ws + OFF_Y0);
    float*    z1      = (float*)(ws + OFF_Z1);

    hipMemsetAsync(col_cnt, 0, MEMSET_BYTES, stream);

    k_scan_gemm<<<NN + NN / 4, 256, 0, stream>>>(B1, x0, W0, row_cnt, col_cnt,
            csr_col, csc_row, y0);
    k_rowscale<<<NN / 4, 256, 0, stream>>>(row_cnt, col_cnt, csr_col, rscale, y0);
    k_edge_fused<<<NE / 4, 256, 0, stream>>>(col_cnt, csc_row, row_cnt, y0,
            b01, W1, z1, out + NN * 64);
    k_node_gather<<<NN / 4, 256, 0, stream>>>(row_cnt, csr_col, rscale, z1, b10, out);
}